// Round 5
// baseline (125.683 us; speedup 1.0000x reference)
//
#include <hip/hip_runtime.h>

// ContextGenerator: B=32, D=NOTE_RES=64, T=4096, fp32.
// res[b,t] = sum_{L=low..min(63,up-1)} dm[b,L-1,t] * s_L[t]
// Group M (L=M+pad, pad in [0,M)):  s_L = P_M(pad) + sum_{k=pad}^{M-1} xC[k]*pm[k+pad]
//   where xC = down^{log2(64/M)}(rep column), P_M(pad) = sum_{w<2pad} xF[w]*pm[w].
//
// R4: LDS-read-count attack. R1/R3 both ~30us because every FMA re-read an
// LDS operand (~1160 ds_read_b32/block ~= 22us of LDS pipe). Now each wave
// caches its distinct rows in registers ONCE and FMAs are reg-reg.
// 6 waves/block, one 64-t slice, k-split of group32's coarse term:
//   w0: k in [24,32)   w1: k in [16,24)   w2: k in [8,16)
//   w3: k in [0,8) + M=16 level           w4: group32 prefix P_32(pad) duty
//   w5: M=8,4,2,1 levels
// Staging identical to R3 (width-16 global_load_lds, 48 insts).

#define TT 4096

__device__ __forceinline__ void async_load16(const float* g, float* l) {
  __builtin_amdgcn_global_load_lds(
      (const __attribute__((address_space(1))) void*)g,
      (__attribute__((address_space(3))) void*)l, 16, 0, 0);
}

// Coarse-term k-range [K0, K0+8) of group32 (M=32). Reads: rep rows
// [2K0, 2K0+16), pm rows [K0, min(62, 2K0+14)], dm rows 31..31+PADN-1.
template <int K0>
__device__ __forceinline__ float roleK(const float* __restrict__ lrep,
                                       const float* __restrict__ lpm,
                                       const float* __restrict__ ldm, int lane,
                                       int low, int up) {
  constexpr int PADN = (K0 + 8 < 32) ? (K0 + 8) : 32;       // pads 0..PADN-1
  constexpr int PMN = (2 * K0 + 14 < 62 ? 2 * K0 + 14 : 62) - K0 + 1;
  float xa[8];  // x1[K0..K0+7]
#pragma unroll
  for (int i = 0; i < 8; ++i)
    xa[i] = 0.5f * (lrep[(2 * (K0 + i)) * 64 + lane] +
                    lrep[(2 * (K0 + i) + 1) * 64 + lane]);
  float pmv[PMN];
#pragma unroll
  for (int r = 0; r < PMN; ++r) pmv[r] = lpm[(K0 + r) * 64 + lane];
  float res = 0.f;
#pragma unroll
  for (int pad = 0; pad < PADN; ++pad) {
    const int L = 32 + pad;
    const int kk0 = (pad > K0) ? pad : K0;
    float s = 0.f;
#pragma unroll
    for (int k = kk0; k < K0 + 8; ++k)
      s = fmaf(xa[k - K0], pmv[k + pad - K0], s);
    if (L >= low && L < up) res = fmaf(ldm[(31 + pad) * 64 + lane], s, res);
  }
  return res;
}

// w3: group32 coarse k in [0,8)  +  the whole M=16 level.
__device__ __forceinline__ float role3(const float* __restrict__ lrep,
                                       const float* __restrict__ lpm,
                                       const float* __restrict__ ldm, int lane,
                                       int low, int up) {
  float pmv[31];  // pm rows 0..30
#pragma unroll
  for (int r = 0; r < 31; ++r) pmv[r] = lpm[r * 64 + lane];
  float x1[32];
#pragma unroll
  for (int j = 0; j < 32; ++j)
    x1[j] = 0.5f * (lrep[(2 * j) * 64 + lane] + lrep[(2 * j + 1) * 64 + lane]);
  float res = 0.f;
  // group32, k in [0,8): pads 0..7, pm rows 0..14
#pragma unroll
  for (int pad = 0; pad < 8; ++pad) {
    const int L = 32 + pad;
    float s = 0.f;
#pragma unroll
    for (int k = pad; k < 8; ++k) s = fmaf(x1[k], pmv[k + pad], s);
    if (L >= low && L < up) res = fmaf(ldm[(31 + pad) * 64 + lane], s, res);
  }
  // M=16 level: coarse x2, fine x1 (prefix q1), pm rows 0..30, dm rows 15..30
  float x2[16], q1[16];
#pragma unroll
  for (int j = 0; j < 16; ++j) {
    const float a = x1[2 * j], b = x1[2 * j + 1];
    x2[j] = 0.5f * (a + b);
    q1[j] = a * pmv[2 * j] + b * pmv[2 * j + 1];
  }
  float p = 0.f;
#pragma unroll
  for (int pad = 0; pad < 16; ++pad) {
    const int L = 16 + pad;
    float s = p;
#pragma unroll
    for (int k = pad; k < 16; ++k) s = fmaf(x2[k], pmv[k + pad], s);
    if (L >= low && L < up) res = fmaf(ldm[(15 + pad) * 64 + lane], s, res);
    p += q1[pad];
  }
  return res;
}

// w4: group32 fine-prefix duty: sum_pad dm[31+pad] * P_32(pad),
// P_32(pad) = sum_{j<pad} (rep[2j]pm[2j] + rep[2j+1]pm[2j+1]).
__device__ __forceinline__ float role4(const float* __restrict__ lrep,
                                       const float* __restrict__ lpm,
                                       const float* __restrict__ ldm, int lane,
                                       int low, int up) {
  float res = 0.f, p = 0.f;
#pragma unroll
  for (int pad = 1; pad < 32; ++pad) {
    const int j = pad - 1;
    const float a = lrep[(2 * j) * 64 + lane];
    const float b = lrep[(2 * j + 1) * 64 + lane];
    const float pa = lpm[(2 * j) * 64 + lane];
    const float pb = lpm[(2 * j + 1) * 64 + lane];
    p = fmaf(a, pa, fmaf(b, pb, p));
    const int L = 32 + pad;
    if (L >= low && L < up) res = fmaf(ldm[(31 + pad) * 64 + lane], p, res);
  }
  return res;
}

// w5: M=8,4,2,1 levels. pm rows 0..14, dm rows 0..14, rep all (via x1,x2).
template <int M>
__device__ __forceinline__ void level_step(const float* pmv,
                                           const float* __restrict__ ldm,
                                           int lane, int low, int up, float* xf,
                                           float* xc, float& res) {
  float q[M];
#pragma unroll
  for (int j = 0; j < M; ++j) {
    const float a = xf[2 * j], b = xf[2 * j + 1];
    xc[j] = 0.5f * (a + b);
    q[j] = a * pmv[2 * j] + b * pmv[2 * j + 1];
  }
  float p = 0.f;
#pragma unroll
  for (int pad = 0; pad < M; ++pad) {
    const int L = M + pad;
    float s = p;
#pragma unroll
    for (int k = pad; k < M; ++k) s = fmaf(xc[k], pmv[k + pad], s);
    if (L >= low && L < up) res = fmaf(ldm[(M - 1 + pad) * 64 + lane], s, res);
    p += q[pad];
  }
}

__device__ __forceinline__ float role5(const float* __restrict__ lrep,
                                       const float* __restrict__ lpm,
                                       const float* __restrict__ ldm, int lane,
                                       int low, int up) {
  float pmv[15];  // pm rows 0..14
#pragma unroll
  for (int r = 0; r < 15; ++r) pmv[r] = lpm[r * 64 + lane];
  float x1[32];
#pragma unroll
  for (int j = 0; j < 32; ++j)
    x1[j] = 0.5f * (lrep[(2 * j) * 64 + lane] + lrep[(2 * j + 1) * 64 + lane]);
  float x2[16];
#pragma unroll
  for (int j = 0; j < 16; ++j) x2[j] = 0.5f * (x1[2 * j] + x1[2 * j + 1]);
  float res = 0.f;
  float x3[8], x4[4], x5[2], x6[1];
  level_step<8>(pmv, ldm, lane, low, up, x2, x3, res);
  level_step<4>(pmv, ldm, lane, low, up, x3, x4, res);
  level_step<2>(pmv, ldm, lane, low, up, x4, x5, res);
  level_step<1>(pmv, ldm, lane, low, up, x5, x6, res);
  return res;
}

__global__ __launch_bounds__(384, 3) void ContextGenerator_34875134444049_kernel(
    const float* __restrict__ rep, const float* __restrict__ dm,
    const float* __restrict__ pm, const int* __restrict__ lowp,
    const int* __restrict__ upp, float* __restrict__ out) {
  // 192 data rows (64 rep | 64 pm | 64 dm) * 256 B + 6*64 partials = 50688 B
  __shared__ float lds[192 * 64 + 6 * 64];
  const int wid = threadIdx.x >> 6;
  const int lane = threadIdx.x & 63;
  const int b = blockIdx.x >> 6;          // 2048 blocks: 64 chunks per batch
  const int t0 = (blockIdx.x & 63) << 6;  // 64-t slice
  const size_t base = (size_t)b * 64 * TT + (size_t)t0;

  // Width-16 staging: instruction g stages rows 4g..4g+3 (1 KB).
  const size_t lv = (size_t)(lane >> 4) * TT + (size_t)((lane & 15) << 2);
  for (int g = wid; g < 48; g += 6) {  // wave-uniform g
    const float* tbase = (g < 16) ? rep + base
                       : (g < 32) ? pm + base - (size_t)64 * TT
                                  : dm + base - (size_t)128 * TT;
    const float* src = tbase + (size_t)(g << 2) * TT + lv;
    async_load16(src, &lds[g * 256]);
  }

  const int low = lowp[0];
  const int up = upp[0];

  __syncthreads();  // drains global_load_lds (vmcnt) + barrier

  const float* lrep = lds;
  const float* lpm = lds + 64 * 64;
  const float* ldm = lds + 128 * 64;
  float* part = lds + 192 * 64;

  float res;
  if (wid == 0)
    res = roleK<24>(lrep, lpm, ldm, lane, low, up);
  else if (wid == 1)
    res = roleK<16>(lrep, lpm, ldm, lane, low, up);
  else if (wid == 2)
    res = roleK<8>(lrep, lpm, ldm, lane, low, up);
  else if (wid == 3)
    res = role3(lrep, lpm, ldm, lane, low, up);
  else if (wid == 4)
    res = role4(lrep, lpm, ldm, lane, low, up);
  else
    res = role5(lrep, lpm, ldm, lane, low, up);

  if (wid > 0) part[wid * 64 + lane] = res;
  __syncthreads();
  if (wid == 0)
    out[(size_t)b * TT + t0 + lane] = res + part[64 + lane] + part[128 + lane] +
                                      part[192 + lane] + part[256 + lane] +
                                      part[320 + lane];
}

extern "C" void kernel_launch(void* const* d_in, const int* in_sizes, int n_in,
                              void* d_out, int out_size, void* d_ws,
                              size_t ws_size, hipStream_t stream) {
  const float* rep = (const float*)d_in[0];
  const float* dm = (const float*)d_in[1];
  const float* pm = (const float*)d_in[2];
  const int* lowp = (const int*)d_in[3];
  const int* upp = (const int*)d_in[4];
  float* out = (float*)d_out;

  const int blocks = out_size / 64;  // 131072 / 64 = 2048
  ContextGenerator_34875134444049_kernel<<<blocks, 384, 0, stream>>>(
      rep, dm, pm, lowp, upp, out);
}